// Round 1
// baseline (2776.980 us; speedup 1.0000x reference)
//
#include <hip/hip_runtime.h>
#include <cstdint>

#define L_DIM 2048
#define B_DIM 16
#define D_DIM 1024
#define M_DIM (L_DIM*B_DIM)   // 32768
#define N_DIM (3*D_DIM)       // 3072
#define K_DIM D_DIM           // 1024

typedef __bf16 bf16x8 __attribute__((ext_vector_type(8)));
typedef float f32x4 __attribute__((ext_vector_type(4)));

__device__ inline float bf2f(ushort u){ return __uint_as_float(((unsigned)u)<<16); }
__device__ inline ushort f2bf(float f){
  unsigned u = __float_as_uint(f);
  u += 0x7fffu + ((u>>16)&1u);          // RTNE
  return (ushort)(u>>16);
}

// fp32 -> bf16 convert, 8 elements per thread
__global__ __launch_bounds__(256) void cvt8(const float* __restrict__ in,
                                            ushort* __restrict__ out, int n8){
  int t = blockIdx.x*256 + threadIdx.x;
  if (t >= n8) return;
  const float4* p = (const float4*)(in + (size_t)t*8);
  float4 a = p[0], b = p[1];
  ushort r[8] = {f2bf(a.x),f2bf(a.y),f2bf(a.z),f2bf(a.w),
                 f2bf(b.x),f2bf(b.y),f2bf(b.z),f2bf(b.w)};
  *(uint4*)(out + (size_t)t*8) = *(const uint4*)r;
}

// C[m,o] = sum_k A[m,k]*Bt[o,k] + bias[o]; epilogue: region 0 -> x (raw),
// region 1 -> z = sigmoid, region 2 -> h_gate = sigmoid. All bf16 out.
__global__ __launch_bounds__(256) void gemm_sru(
    const ushort* __restrict__ A,   // M x K bf16
    const ushort* __restrict__ Bt,  // N x K bf16
    const float* __restrict__ bias, // N fp32
    ushort* __restrict__ xbuf, ushort* __restrict__ zbuf, ushort* __restrict__ hbuf)
{
  __shared__ ushort As[128*32];
  __shared__ ushort Bs[128*32];
  const int tid  = threadIdx.x;
  const int lane = tid & 63, w = tid >> 6;
  const int wm = w >> 1, wn = w & 1;           // 2x2 wave grid, 64x64 each
  const int bnb = blockIdx.x % (N_DIM/128);
  const int bmb = blockIdx.x / (N_DIM/128);
  const int bm = bmb*128, bn = bnb*128;

  f32x4 acc[4][4];
  #pragma unroll
  for (int i=0;i<4;i++)
    #pragma unroll
    for (int j=0;j<4;j++) acc[i][j] = (f32x4){0.f,0.f,0.f,0.f};

  const int lrow = lane & 15, lk = (lane>>4)*8;

  for (int k0 = 0; k0 < K_DIM; k0 += 32) {
    #pragma unroll
    for (int q=0;q<2;q++){
      int c = (w*2+q)*64 + lane;               // chunk 0..511, 16B each
      int row = c >> 2, k8 = (c&3)*8;
      __builtin_amdgcn_global_load_lds(
        (const __attribute__((address_space(1))) void*)(A + (size_t)(bm+row)*K_DIM + k0 + k8),
        (__attribute__((address_space(3))) void*)(As + c*8), 16, 0, 0);
      __builtin_amdgcn_global_load_lds(
        (const __attribute__((address_space(1))) void*)(Bt + (size_t)(bn+row)*K_DIM + k0 + k8),
        (__attribute__((address_space(3))) void*)(Bs + c*8), 16, 0, 0);
    }
    __syncthreads();

    bf16x8 af[4], bf[4];
    #pragma unroll
    for (int i=0;i<4;i++) af[i] = *(const bf16x8*)(As + (wm*64 + i*16 + lrow)*32 + lk);
    #pragma unroll
    for (int j=0;j<4;j++) bf[j] = *(const bf16x8*)(Bs + (wn*64 + j*16 + lrow)*32 + lk);
    #pragma unroll
    for (int i=0;i<4;i++)
      #pragma unroll
      for (int j=0;j<4;j++)
        acc[i][j] = __builtin_amdgcn_mfma_f32_16x16x32_bf16(af[i], bf[j], acc[i][j], 0,0,0);
    __syncthreads();
  }

  // epilogue: C/D layout col = lane&15, row = (lane>>4)*4 + r  [verified m89/m91]
  const int region = bn >> 10;                  // 128-wide tile lies in one region
  ushort* dst = region==0 ? xbuf : (region==1 ? zbuf : hbuf);
  #pragma unroll
  for (int j=0;j<4;j++){
    int o = bn + wn*64 + j*16 + lrow;
    float bv = bias[o];
    int colr = o & (D_DIM-1);
    #pragma unroll
    for (int i=0;i<4;i++){
      #pragma unroll
      for (int r=0;r<4;r++){
        int m = bm + wm*64 + i*16 + (lane>>4)*4 + r;
        float v = acc[i][j][r] + bv;
        if (region) v = 1.f/(1.f + __expf(-v));
        dst[(size_t)m*D_DIM + colr] = f2bf(v);
      }
    }
  }
}

// sequential scan over L, one thread per (b,d) channel; fused output blend
__global__ __launch_bounds__(64) void scan_sru(
    const ushort* __restrict__ z, const ushort* __restrict__ x, const ushort* __restrict__ hg,
    const float* __restrict__ prev, const float* __restrict__ h0,
    float* __restrict__ out, float* __restrict__ hfin)
{
  int c = blockIdx.x*64 + threadIdx.x;          // 0..16383
  float s = h0[c];
  size_t idx = c;
  #pragma unroll 8
  for (int l=0; l<L_DIM; ++l, idx += (size_t)B_DIM*D_DIM) {
    float zv = bf2f(z[idx]);
    float xv = bf2f(x[idx]);
    s += zv * (xv - s);                          // (1-z)s + z x
    float hv = bf2f(hg[idx]);
    out[idx] = s + hv * (prev[idx] - s);         // (1-hg)s + hg*prev
  }
  hfin[c] = s;
}

extern "C" void kernel_launch(void* const* d_in, const int* in_sizes, int n_in,
                              void* d_out, int out_size, void* d_ws, size_t ws_size,
                              hipStream_t stream) {
  const float* prev = (const float*)d_in[0];   // (L,B,D)
  const float* h0   = (const float*)d_in[1];   // (B,D)
  const float* W    = (const float*)d_in[2];   // (3D,D)
  const float* bias = (const float*)d_in[3];   // (3D,)
  float* out  = (float*)d_out;
  float* hfin = out + (size_t)M_DIM*D_DIM;

  char* ws = (char*)d_ws;
  ushort* Ab = (ushort*)ws;                                        // 64 MiB
  ushort* Wb = (ushort*)(ws + (size_t)M_DIM*K_DIM*2);              // 6 MiB
  ushort* xb = (ushort*)(ws + (size_t)M_DIM*K_DIM*2 + (size_t)N_DIM*K_DIM*2);
  ushort* zb = xb + (size_t)M_DIM*D_DIM;
  ushort* hb = zb + (size_t)M_DIM*D_DIM;

  cvt8<<<(M_DIM*K_DIM/8 + 255)/256, 256, 0, stream>>>(prev, Ab, M_DIM*K_DIM/8);
  cvt8<<<(N_DIM*K_DIM/8 + 255)/256, 256, 0, stream>>>(W,    Wb, N_DIM*K_DIM/8);
  gemm_sru<<<(M_DIM/128)*(N_DIM/128), 256, 0, stream>>>(Ab, Wb, bias, xb, zb, hb);
  scan_sru<<<(B_DIM*D_DIM)/64, 64, 0, stream>>>(zb, xb, hb, prev, h0, out, hfin);
}

// Round 3
// 433.997 us; speedup vs baseline: 6.3986x; 6.3986x over previous
//
#include <hip/hip_runtime.h>
#include <cstdint>

#define L_DIM 2048
#define B_DIM 16
#define D_DIM 1024
#define M_DIM (L_DIM*B_DIM)   // 32768
#define N_DIM (3*D_DIM)       // 3072
#define K_DIM D_DIM           // 1024
#define NCH   (B_DIM*D_DIM)   // 16384 channels
#define SEG   64
#define SEGLEN (L_DIM/SEG)    // 32
#define CG    (NCH/8)         // 2048 channel-groups of 8

typedef __bf16 bf16x8 __attribute__((ext_vector_type(8)));
typedef float f32x4 __attribute__((ext_vector_type(4)));

__device__ inline float bf2f(ushort u){ return __uint_as_float(((unsigned)u)<<16); }
__device__ inline ushort f2bf(float f){
  unsigned u = __float_as_uint(f);
  u += 0x7fffu + ((u>>16)&1u);          // RTNE
  return (ushort)(u>>16);
}

// fp32 -> bf16 convert, 8 elements per thread
__global__ __launch_bounds__(256) void cvt8(const float* __restrict__ in,
                                            ushort* __restrict__ out, int n8){
  int t = blockIdx.x*256 + threadIdx.x;
  if (t >= n8) return;
  const float4* p = (const float4*)(in + (size_t)t*8);
  float4 a = p[0], b = p[1];
  ushort r[8] = {f2bf(a.x),f2bf(a.y),f2bf(a.z),f2bf(a.w),
                 f2bf(b.x),f2bf(b.y),f2bf(b.z),f2bf(b.w)};
  *(uint4*)(out + (size_t)t*8) = *(const uint4*)r;
}

// C[m,o] = sum_k A[m,k]*Bt[o,k] + bias[o]; region 0 -> x (raw),
// region 1 -> z = sigmoid, region 2 -> h_gate = sigmoid. All bf16 out.
__global__ __launch_bounds__(256) void gemm_sru(
    const ushort* __restrict__ A,   // M x K bf16
    const ushort* __restrict__ Bt,  // N x K bf16
    const float* __restrict__ bias, // N fp32
    ushort* __restrict__ xbuf, ushort* __restrict__ zbuf, ushort* __restrict__ hbuf)
{
  __shared__ ushort As[128*32];
  __shared__ ushort Bs[128*32];
  const int tid  = threadIdx.x;
  const int lane = tid & 63, w = tid >> 6;
  const int wm = w >> 1, wn = w & 1;           // 2x2 wave grid, 64x64 each
  const int bnb = blockIdx.x % (N_DIM/128);
  const int bmb = blockIdx.x / (N_DIM/128);
  const int bm = bmb*128, bn = bnb*128;

  f32x4 acc[4][4];
  #pragma unroll
  for (int i=0;i<4;i++)
    #pragma unroll
    for (int j=0;j<4;j++) acc[i][j] = (f32x4){0.f,0.f,0.f,0.f};

  const int lrow = lane & 15, lk = (lane>>4)*8;

  for (int k0 = 0; k0 < K_DIM; k0 += 32) {
    #pragma unroll
    for (int q=0;q<2;q++){
      int c = (w*2+q)*64 + lane;               // chunk 0..511, 16B each
      int row = c >> 2, k8 = (c&3)*8;
      __builtin_amdgcn_global_load_lds(
        (const __attribute__((address_space(1))) void*)(A + (size_t)(bm+row)*K_DIM + k0 + k8),
        (__attribute__((address_space(3))) void*)(As + c*8), 16, 0, 0);
      __builtin_amdgcn_global_load_lds(
        (const __attribute__((address_space(1))) void*)(Bt + (size_t)(bn+row)*K_DIM + k0 + k8),
        (__attribute__((address_space(3))) void*)(Bs + c*8), 16, 0, 0);
    }
    __syncthreads();

    bf16x8 af[4], bf[4];
    #pragma unroll
    for (int i=0;i<4;i++) af[i] = *(const bf16x8*)(As + (wm*64 + i*16 + lrow)*32 + lk);
    #pragma unroll
    for (int j=0;j<4;j++) bf[j] = *(const bf16x8*)(Bs + (wn*64 + j*16 + lrow)*32 + lk);
    #pragma unroll
    for (int i=0;i<4;i++)
      #pragma unroll
      for (int j=0;j<4;j++)
        acc[i][j] = __builtin_amdgcn_mfma_f32_16x16x32_bf16(af[i], bf[j], acc[i][j], 0,0,0);
    __syncthreads();
  }

  const int region = bn >> 10;                  // 128-wide tile lies in one region
  ushort* dst = region==0 ? xbuf : (region==1 ? zbuf : hbuf);
  #pragma unroll
  for (int j=0;j<4;j++){
    int o = bn + wn*64 + j*16 + lrow;
    float bv = bias[o];
    int colr = o & (D_DIM-1);
    #pragma unroll
    for (int i=0;i<4;i++){
      #pragma unroll
      for (int r=0;r<4;r++){
        int m = bm + wm*64 + i*16 + (lane>>4)*4 + r;
        float v = acc[i][j][r] + bv;
        if (region) v = 1.f/(1.f + __expf(-v));
        dst[(size_t)m*D_DIM + colr] = f2bf(v);
      }
    }
  }
}

// Pass 1: per (segment, 8-channel group) compose affine coefficients
// s' = a*s + b with a = 1-z, b = z*x ; segment transform (A = prod a, B)
__global__ __launch_bounds__(256) void scan_pass1(
    const ushort* __restrict__ z, const ushort* __restrict__ x,
    float* __restrict__ Aout, float* __restrict__ Bout)
{
  int t = blockIdx.x*256 + threadIdx.x;   // 0..131071
  int cg = t & (CG-1), g = t >> 11;       // CG = 2048 = 2^11
  int c0 = cg*8;
  size_t base = (size_t)g*SEGLEN*NCH + c0;
  float A[8], Bc[8];
  #pragma unroll
  for (int j=0;j<8;j++){ A[j]=1.f; Bc[j]=0.f; }
  #pragma unroll 4
  for (int i=0;i<SEGLEN;i++){
    uint4 zv = *(const uint4*)(z + base + (size_t)i*NCH);
    uint4 xv = *(const uint4*)(x + base + (size_t)i*NCH);
    const ushort* zp = (const ushort*)&zv;
    const ushort* xp = (const ushort*)&xv;
    #pragma unroll
    for (int j=0;j<8;j++){
      float zf = bf2f(zp[j]);
      float a  = 1.f - zf;
      float b  = zf * bf2f(xp[j]);
      Bc[j] = a*Bc[j] + b;
      A[j]  = a*A[j];
    }
  }
  float* Ao = Aout + (size_t)g*NCH + c0;
  float* Bo = Bout + (size_t)g*NCH + c0;
  *(float4*)Ao     = make_float4(A[0],A[1],A[2],A[3]);
  *(float4*)(Ao+4) = make_float4(A[4],A[5],A[6],A[7]);
  *(float4*)Bo     = make_float4(Bc[0],Bc[1],Bc[2],Bc[3]);
  *(float4*)(Bo+4) = make_float4(Bc[4],Bc[5],Bc[6],Bc[7]);
}

// Pass 2: sequential scan over the 64 segment summaries per channel
__global__ __launch_bounds__(256) void scan_pass2(
    const float* __restrict__ A, const float* __restrict__ B,
    const float* __restrict__ h0, float* __restrict__ seg, float* __restrict__ hfin)
{
  int c = blockIdx.x*256 + threadIdx.x;   // 0..16383
  float s = h0[c];
  #pragma unroll 8
  for (int g=0; g<SEG; g++){
    seg[(size_t)g*NCH + c] = s;
    s = A[(size_t)g*NCH + c]*s + B[(size_t)g*NCH + c];
  }
  hfin[c] = s;
}

// Pass 3: replay each segment from its start state, fused output blend
__global__ __launch_bounds__(256) void scan_pass3(
    const ushort* __restrict__ z, const ushort* __restrict__ x, const ushort* __restrict__ hg,
    const float* __restrict__ prev, const float* __restrict__ seg,
    float* __restrict__ out)
{
  int t = blockIdx.x*256 + threadIdx.x;   // 0..131071
  int cg = t & (CG-1), g = t >> 11;
  int c0 = cg*8;
  float s[8];
  *(float4*)s     = *(const float4*)(seg + (size_t)g*NCH + c0);
  *(float4*)(s+4) = *(const float4*)(seg + (size_t)g*NCH + c0 + 4);
  size_t base = (size_t)g*SEGLEN*NCH + c0;
  #pragma unroll 2
  for (int i=0;i<SEGLEN;i++){
    size_t idx = base + (size_t)i*NCH;
    uint4 zv = *(const uint4*)(z+idx);
    uint4 xv = *(const uint4*)(x+idx);
    uint4 hv = *(const uint4*)(hg+idx);
    float4 p0 = *(const float4*)(prev+idx);
    float4 p1 = *(const float4*)(prev+idx+4);
    const ushort* zp=(const ushort*)&zv;
    const ushort* xp=(const ushort*)&xv;
    const ushort* hp=(const ushort*)&hv;
    float pv[8] = {p0.x,p0.y,p0.z,p0.w,p1.x,p1.y,p1.z,p1.w};
    float o[8];
    #pragma unroll
    for (int j=0;j<8;j++){
      float zf = bf2f(zp[j]);
      s[j] += zf*(bf2f(xp[j]) - s[j]);
      float hf = bf2f(hp[j]);
      o[j] = s[j] + hf*(pv[j] - s[j]);
    }
    *(float4*)(out+idx)   = make_float4(o[0],o[1],o[2],o[3]);
    *(float4*)(out+idx+4) = make_float4(o[4],o[5],o[6],o[7]);
  }
}

extern "C" void kernel_launch(void* const* d_in, const int* in_sizes, int n_in,
                              void* d_out, int out_size, void* d_ws, size_t ws_size,
                              hipStream_t stream) {
  const float* prev = (const float*)d_in[0];   // (L,B,D)
  const float* h0   = (const float*)d_in[1];   // (B,D)
  const float* W    = (const float*)d_in[2];   // (3D,D)
  const float* bias = (const float*)d_in[3];   // (3D,)
  float* out  = (float*)d_out;
  float* hfin = out + (size_t)M_DIM*D_DIM;

  char* ws = (char*)d_ws;
  ushort* Ab = (ushort*)ws;                                        // 64 MiB (dead after gemm)
  ushort* Wb = (ushort*)(ws + (size_t)M_DIM*K_DIM*2);              // 6 MiB
  ushort* xb = (ushort*)(ws + (size_t)M_DIM*K_DIM*2 + (size_t)N_DIM*K_DIM*2);
  ushort* zb = xb + (size_t)M_DIM*D_DIM;
  ushort* hb = zb + (size_t)M_DIM*D_DIM;
  // overlay scan scratch on Ab's region (only live after gemm completes)
  float* Abuf = (float*)ws;                     // SEG*NCH floats = 4 MiB
  float* Bbuf = Abuf + (size_t)SEG*NCH;         // 4 MiB
  float* segb = Bbuf + (size_t)SEG*NCH;         // 4 MiB

  cvt8<<<(M_DIM*K_DIM/8 + 255)/256, 256, 0, stream>>>(prev, Ab, M_DIM*K_DIM/8);
  cvt8<<<(N_DIM*K_DIM/8 + 255)/256, 256, 0, stream>>>(W,    Wb, N_DIM*K_DIM/8);
  gemm_sru<<<(M_DIM/128)*(N_DIM/128), 256, 0, stream>>>(Ab, Wb, bias, xb, zb, hb);
  scan_pass1<<<(CG*SEG)/256, 256, 0, stream>>>(zb, xb, Abuf, Bbuf);
  scan_pass2<<<NCH/256, 256, 0, stream>>>(Abuf, Bbuf, h0, segb, hfin);
  scan_pass3<<<(CG*SEG)/256, 256, 0, stream>>>(zb, xb, hb, prev, segb, out);
}

// Round 4
// 422.393 us; speedup vs baseline: 6.5744x; 1.0275x over previous
//
#include <hip/hip_runtime.h>
#include <cstdint>

#define L_DIM 2048
#define B_DIM 16
#define D_DIM 1024
#define M_DIM (L_DIM*B_DIM)   // 32768
#define N_DIM (3*D_DIM)       // 3072
#define K_DIM D_DIM           // 1024
#define NCH   (B_DIM*D_DIM)   // 16384 channels
#define SEG   64
#define SEGLEN (L_DIM/SEG)    // 32
#define CG    (NCH/8)         // 2048 channel-groups of 8

#define BK 32                 // K per tile-step
#define NKT (K_DIM/BK)        // 32 K-tiles
#define BUFB 32768            // bytes per LDS buffer (A 16KB + B 16KB)

typedef __bf16 bf16x8 __attribute__((ext_vector_type(8)));
typedef float f32x4 __attribute__((ext_vector_type(4)));

__device__ inline float bf2f(ushort u){ return __uint_as_float(((unsigned)u)<<16); }
__device__ inline ushort f2bf(float f){
  unsigned u = __float_as_uint(f);
  u += 0x7fffu + ((u>>16)&1u);          // RTNE
  return (ushort)(u>>16);
}

// fp32 -> bf16 convert, 8 elements per thread
__global__ __launch_bounds__(256) void cvt8(const float* __restrict__ in,
                                            ushort* __restrict__ out, int n8){
  int t = blockIdx.x*256 + threadIdx.x;
  if (t >= n8) return;
  const float4* p = (const float4*)(in + (size_t)t*8);
  float4 a = p[0], b = p[1];
  ushort r[8] = {f2bf(a.x),f2bf(a.y),f2bf(a.z),f2bf(a.w),
                 f2bf(b.x),f2bf(b.y),f2bf(b.z),f2bf(b.w)};
  *(uint4*)(out + (size_t)t*8) = *(const uint4*)r;
}

// 256x256 tile, BK=32, 8 waves (2Mx4N), 4-buffer LDS pipeline w/ counted vmcnt.
// C[m,o] = sum_k A[m,k]*Bt[o,k] + bias[o]; region 0 -> x, 1 -> z=sigmoid, 2 -> hg=sigmoid.
__global__ __launch_bounds__(512, 2) void gemm_sru(
    const ushort* __restrict__ gA,  // M x K bf16
    const ushort* __restrict__ gB,  // N x K bf16
    const float* __restrict__ bias, // N fp32
    ushort* __restrict__ xbuf, ushort* __restrict__ zbuf, ushort* __restrict__ hbuf)
{
  __shared__ ushort lds[4*BUFB/2];   // 128 KiB
  char* ldsb = (char*)lds;

  const int tid  = threadIdx.x;
  const int lane = tid & 63, w = tid >> 6;
  const int wm = w >> 2, wn = w & 3;             // 2x4 wave grid; per-wave 128x64

  // XCD-chunked block swizzle (nwg=1536, %8==0 -> simple bijective form)
  const int bid = blockIdx.x;
  const int swz = (bid & 7)*192 + (bid >> 3);
  const int bmb = swz / (N_DIM/256), bnb = swz % (N_DIM/256);
  const int bm = bmb*256, bn = bnb*256;

  // ds_read addressing (logical row, 16B slot c16; swizzled slot = c16 ^ ((row>>1)&3))
  const int xr     = (lane>>1) & 3;
  const int cxor16 = ((lane>>4) ^ xr) * 16;      // byte offset of swizzled 16B slot
  const int arow   = wm*128 + (lane & 15);       // A logical row base (per-lane)
  const int brow   = wn*64  + (lane & 15);       // B logical row base (per-lane)

  // staging addressing: thread covers 16B chunk; chunk = ld*512 + tid
  const int srow0 = tid >> 2;                    // ld=0 rows 0..127
  const int srow1 = 128 + (tid >> 2);            // ld=1 rows 128..255
  const int sc16p = (tid & 3) ^ ((tid >> 3) & 3);// pre-swizzled global 16B slot
  const int cb0 = tid*16, cb1 = 8192 + tid*16;   // LDS chunk byte offsets (linear dest)

  f32x4 acc[8][4];
  #pragma unroll
  for (int i=0;i<8;i++)
    #pragma unroll
    for (int j=0;j<4;j++) acc[i][j] = (f32x4){0.f,0.f,0.f,0.f};

  auto stageA = [&](int t){
    int k0 = t*BK;
    char* dst = ldsb + (t&3)*BUFB;
    __builtin_amdgcn_global_load_lds(
      (const __attribute__((address_space(1))) void*)(gA + (size_t)(bm+srow0)*K_DIM + k0 + sc16p*8),
      (__attribute__((address_space(3))) void*)(dst + cb0), 16, 0, 0);
    __builtin_amdgcn_global_load_lds(
      (const __attribute__((address_space(1))) void*)(gA + (size_t)(bm+srow1)*K_DIM + k0 + sc16p*8),
      (__attribute__((address_space(3))) void*)(dst + cb1), 16, 0, 0);
  };
  auto stageB = [&](int t){
    int k0 = t*BK;
    char* dst = ldsb + (t&3)*BUFB + 16384;
    __builtin_amdgcn_global_load_lds(
      (const __attribute__((address_space(1))) void*)(gB + (size_t)(bn+srow0)*K_DIM + k0 + sc16p*8),
      (__attribute__((address_space(3))) void*)(dst + cb0), 16, 0, 0);
    __builtin_amdgcn_global_load_lds(
      (const __attribute__((address_space(1))) void*)(gB + (size_t)(bn+srow1)*K_DIM + k0 + sc16p*8),
      (__attribute__((address_space(3))) void*)(dst + cb1), 16, 0, 0);
  };

  // prologue: stage K0,K1,K2 (12 loads); wait oldest 4 (K0) done
  stageA(0); stageB(0);
  stageA(1); stageB(1);
  stageA(2); stageB(2);
  asm volatile("s_waitcnt vmcnt(8)" ::: "memory");
  __builtin_amdgcn_s_barrier();
  asm volatile("" ::: "memory");

  for (int t = 0; t < NKT; ++t) {
    const char* A_ = ldsb + (t&3)*BUFB;
    const char* B_ = ldsb + (t&3)*BUFB + 16384;
    const bool st = (t <= NKT-4);               // stage t+3 while processing t

    // ---- phase A: A-frags + B-frags 0,1 ; stage A of t+3 ----
    bf16x8 af[8];
    #pragma unroll
    for (int mf=0; mf<8; ++mf)
      af[mf] = *(const bf16x8*)(A_ + (arow + mf*16)*64 + cxor16);
    bf16x8 bf0 = *(const bf16x8*)(B_ + (brow +  0)*64 + cxor16);
    bf16x8 bf1 = *(const bf16x8*)(B_ + (brow + 16)*64 + cxor16);
    if (st) stageA(t+3);
    asm volatile("" ::: "memory");
    __builtin_amdgcn_s_barrier();
    asm volatile("" ::: "memory");
    __builtin_amdgcn_s_setprio(1);
    #pragma unroll
    for (int mf=0; mf<8; ++mf) {
      acc[mf][0] = __builtin_amdgcn_mfma_f32_16x16x32_bf16(af[mf], bf0, acc[mf][0], 0,0,0);
      acc[mf][1] = __builtin_amdgcn_mfma_f32_16x16x32_bf16(af[mf], bf1, acc[mf][1], 0,0,0);
    }
    __builtin_amdgcn_s_setprio(0);
    asm volatile("" ::: "memory");
    __builtin_amdgcn_s_barrier();
    asm volatile("" ::: "memory");

    // ---- phase B: B-frags 2,3 ; stage B of t+3 ; counted vmcnt ----
    bf16x8 bf2 = *(const bf16x8*)(B_ + (brow + 32)*64 + cxor16);
    bf16x8 bf3 = *(const bf16x8*)(B_ + (brow + 48)*64 + cxor16);
    if (st) stageB(t+3);
    // vmcnt: main loop leaves 8 in flight (K-tiles t+2,t+3); tail drains
    if (t < NKT-3)       asm volatile("s_waitcnt vmcnt(8)" ::: "memory");
    else if (t == NKT-3) asm volatile("s_waitcnt vmcnt(4)" ::: "memory");
    else                 asm volatile("s_waitcnt vmcnt(0)" ::: "memory");
    asm volatile("" ::: "memory");
    __builtin_amdgcn_s_barrier();
    asm volatile("" ::: "memory");
    __builtin_amdgcn_s_setprio(1);
    #pragma unroll
    for (int mf=0; mf<8; ++mf) {
      acc[mf][2] = __builtin_amdgcn_mfma_f32_16x16x32_bf16(af[mf], bf2, acc[mf][2], 0,0,0);
      acc[mf][3] = __builtin_amdgcn_mfma_f32_16x16x32_bf16(af[mf], bf3, acc[mf][3], 0,0,0);
    }
    __builtin_amdgcn_s_setprio(0);
    asm volatile("" ::: "memory");
    __builtin_amdgcn_s_barrier();
    asm volatile("" ::: "memory");
  }

  // epilogue (C/D layout col=lane&15, row=(lane>>4)*4+r — verified m89/m91)
  const int region = bn >> 10;
  ushort* dst = region==0 ? xbuf : (region==1 ? zbuf : hbuf);
  #pragma unroll
  for (int nf=0; nf<4; ++nf){
    int o = bn + wn*64 + nf*16 + (lane & 15);
    float bv = bias[o];
    int colr = o & (D_DIM-1);
    #pragma unroll
    for (int mf=0; mf<8; ++mf){
      #pragma unroll
      for (int r=0;r<4;r++){
        int m = bm + wm*128 + mf*16 + (lane>>4)*4 + r;
        float v = acc[mf][nf][r] + bv;
        if (region) v = 1.f/(1.f + __expf(-v));
        dst[(size_t)m*D_DIM + colr] = f2bf(v);
      }
    }
  }
}

// Pass 1: per (segment, 8-channel group) compose affine coefficients
__global__ __launch_bounds__(256) void scan_pass1(
    const ushort* __restrict__ z, const ushort* __restrict__ x,
    float* __restrict__ Aout, float* __restrict__ Bout)
{
  int t = blockIdx.x*256 + threadIdx.x;   // 0..131071
  int cg = t & (CG-1), g = t >> 11;       // CG = 2048 = 2^11
  int c0 = cg*8;
  size_t base = (size_t)g*SEGLEN*NCH + c0;
  float A[8], Bc[8];
  #pragma unroll
  for (int j=0;j<8;j++){ A[j]=1.f; Bc[j]=0.f; }
  #pragma unroll 4
  for (int i=0;i<SEGLEN;i++){
    uint4 zv = *(const uint4*)(z + base + (size_t)i*NCH);
    uint4 xv = *(const uint4*)(x + base + (size_t)i*NCH);
    const ushort* zp = (const ushort*)&zv;
    const ushort* xp = (const ushort*)&xv;
    #pragma unroll
    for (int j=0;j<8;j++){
      float zf = bf2f(zp[j]);
      float a  = 1.f - zf;
      float b  = zf * bf2f(xp[j]);
      Bc[j] = a*Bc[j] + b;
      A[j]  = a*A[j];
    }
  }
  float* Ao = Aout + (size_t)g*NCH + c0;
  float* Bo = Bout + (size_t)g*NCH + c0;
  *(float4*)Ao     = make_float4(A[0],A[1],A[2],A[3]);
  *(float4*)(Ao+4) = make_float4(A[4],A[5],A[6],A[7]);
  *(float4*)Bo     = make_float4(Bc[0],Bc[1],Bc[2],Bc[3]);
  *(float4*)(Bo+4) = make_float4(Bc[4],Bc[5],Bc[6],Bc[7]);
}

// Pass 2: sequential scan over the 64 segment summaries per channel
__global__ __launch_bounds__(256) void scan_pass2(
    const float* __restrict__ A, const float* __restrict__ B,
    const float* __restrict__ h0, float* __restrict__ seg, float* __restrict__ hfin)
{
  int c = blockIdx.x*256 + threadIdx.x;   // 0..16383
  float s = h0[c];
  #pragma unroll 8
  for (int g=0; g<SEG; g++){
    seg[(size_t)g*NCH + c] = s;
    s = A[(size_t)g*NCH + c]*s + B[(size_t)g*NCH + c];
  }
  hfin[c] = s;
}

// Pass 3: replay each segment from its start state, fused output blend
__global__ __launch_bounds__(256) void scan_pass3(
    const ushort* __restrict__ z, const ushort* __restrict__ x, const ushort* __restrict__ hg,
    const float* __restrict__ prev, const float* __restrict__ seg,
    float* __restrict__ out)
{
  int t = blockIdx.x*256 + threadIdx.x;   // 0..131071
  int cg = t & (CG-1), g = t >> 11;
  int c0 = cg*8;
  float s[8];
  *(float4*)s     = *(const float4*)(seg + (size_t)g*NCH + c0);
  *(float4*)(s+4) = *(const float4*)(seg + (size_t)g*NCH + c0 + 4);
  size_t base = (size_t)g*SEGLEN*NCH + c0;
  #pragma unroll 2
  for (int i=0;i<SEGLEN;i++){
    size_t idx = base + (size_t)i*NCH;
    uint4 zv = *(const uint4*)(z+idx);
    uint4 xv = *(const uint4*)(x+idx);
    uint4 hv = *(const uint4*)(hg+idx);
    float4 p0 = *(const float4*)(prev+idx);
    float4 p1 = *(const float4*)(prev+idx+4);
    const ushort* zp=(const ushort*)&zv;
    const ushort* xp=(const ushort*)&xv;
    const ushort* hp=(const ushort*)&hv;
    float pv[8] = {p0.x,p0.y,p0.z,p0.w,p1.x,p1.y,p1.z,p1.w};
    float o[8];
    #pragma unroll
    for (int j=0;j<8;j++){
      float zf = bf2f(zp[j]);
      s[j] += zf*(bf2f(xp[j]) - s[j]);
      float hf = bf2f(hp[j]);
      o[j] = s[j] + hf*(pv[j] - s[j]);
    }
    *(float4*)(out+idx)   = make_float4(o[0],o[1],o[2],o[3]);
    *(float4*)(out+idx+4) = make_float4(o[4],o[5],o[6],o[7]);
  }
}

extern "C" void kernel_launch(void* const* d_in, const int* in_sizes, int n_in,
                              void* d_out, int out_size, void* d_ws, size_t ws_size,
                              hipStream_t stream) {
  const float* prev = (const float*)d_in[0];   // (L,B,D)
  const float* h0   = (const float*)d_in[1];   // (B,D)
  const float* W    = (const float*)d_in[2];   // (3D,D)
  const float* bias = (const float*)d_in[3];   // (3D,)
  float* out  = (float*)d_out;
  float* hfin = out + (size_t)M_DIM*D_DIM;

  char* ws = (char*)d_ws;
  ushort* Ab = (ushort*)ws;                                        // 64 MiB (dead after gemm)
  ushort* Wb = (ushort*)(ws + (size_t)M_DIM*K_DIM*2);              // 6 MiB
  ushort* xb = (ushort*)(ws + (size_t)M_DIM*K_DIM*2 + (size_t)N_DIM*K_DIM*2);
  ushort* zb = xb + (size_t)M_DIM*D_DIM;
  ushort* hb = zb + (size_t)M_DIM*D_DIM;
  // overlay scan scratch on Ab's region (only live after gemm completes)
  float* Abuf = (float*)ws;                     // SEG*NCH floats = 4 MiB
  float* Bbuf = Abuf + (size_t)SEG*NCH;         // 4 MiB
  float* segb = Bbuf + (size_t)SEG*NCH;         // 4 MiB

  cvt8<<<(M_DIM*K_DIM/8 + 255)/256, 256, 0, stream>>>(prev, Ab, M_DIM*K_DIM/8);
  cvt8<<<(N_DIM*K_DIM/8 + 255)/256, 256, 0, stream>>>(W,    Wb, N_DIM*K_DIM/8);
  gemm_sru<<<(M_DIM/256)*(N_DIM/256), 512, 0, stream>>>(Ab, Wb, bias, xb, zb, hb);
  scan_pass1<<<(CG*SEG)/256, 256, 0, stream>>>(zb, xb, Abuf, Bbuf);
  scan_pass2<<<NCH/256, 256, 0, stream>>>(Abuf, Bbuf, h0, segb, hfin);
  scan_pass3<<<(CG*SEG)/256, 256, 0, stream>>>(zb, xb, hb, prev, segb, out);
}

// Round 6
// 382.047 us; speedup vs baseline: 7.2687x; 1.1056x over previous
//
#include <hip/hip_runtime.h>
#include <cstdint>

#define L_DIM 2048
#define B_DIM 16
#define D_DIM 1024
#define M_DIM (L_DIM*B_DIM)   // 32768
#define N_DIM (3*D_DIM)       // 3072
#define K_DIM D_DIM           // 1024
#define NCH   (B_DIM*D_DIM)   // 16384 channels
#define SEG   64
#define SEGLEN (L_DIM/SEG)    // 32
#define CG    (NCH/8)         // 2048 channel-groups of 8

#define BK 64                 // K per tile-step
#define NKT (K_DIM/BK)        // 16 K-tiles
#define BUF 65536             // bytes per LDS buffer: A 32KB + B 32KB

typedef __bf16 bf16x8 __attribute__((ext_vector_type(8)));
typedef float f32x4 __attribute__((ext_vector_type(4)));

__device__ inline float bf2f(ushort u){ return __uint_as_float(((unsigned)u)<<16); }
__device__ inline ushort f2bf(float f){
  unsigned u = __float_as_uint(f);
  u += 0x7fffu + ((u>>16)&1u);          // RTNE
  return (ushort)(u>>16);
}

// fp32 -> bf16 convert, 8 elements per thread
__global__ __launch_bounds__(256) void cvt8(const float* __restrict__ in,
                                            ushort* __restrict__ out, int n8){
  int t = blockIdx.x*256 + threadIdx.x;
  if (t >= n8) return;
  const float4* p = (const float4*)(in + (size_t)t*8);
  float4 a = p[0], b = p[1];
  ushort r[8] = {f2bf(a.x),f2bf(a.y),f2bf(a.z),f2bf(a.w),
                 f2bf(b.x),f2bf(b.y),f2bf(b.z),f2bf(b.w)};
  *(uint4*)(out + (size_t)t*8) = *(const uint4*)r;
}

#define GLOAD(gp, lp) __builtin_amdgcn_global_load_lds( \
    (const __attribute__((address_space(1))) void*)(gp), \
    (__attribute__((address_space(3))) void*)(lp), 16, 0, 0)

// 256x256 tile, BK=64, 8 waves; m201-style quadrant phases + counted vmcnt.
__global__ __launch_bounds__(512, 2) void gemm_sru(
    const ushort* __restrict__ gA,  // M x K bf16
    const ushort* __restrict__ gB,  // N x K bf16
    const float* __restrict__ bias, // N fp32
    ushort* __restrict__ xbuf, ushort* __restrict__ zbuf, ushort* __restrict__ hbuf)
{
  __shared__ ulong2 lds_[2*BUF/16];   // 128 KiB
  char* ldsb = (char*)lds_;

  const int tid  = threadIdx.x;
  const int lane = tid & 63, w = tid >> 6;
  const int wr = (w>>2)*64;            // wave row base within 128-row quadrant half
  const int wc = (w&3)*32;             // wave col base within 128-col quadrant half

  // XCD-chunked block swizzle (nwg=1536, %8==0 -> bijective)
  const int bid = blockIdx.x;
  const int swz = (bid & 7)*192 + (bid >> 3);
  const int bm = (swz / (N_DIM/256))*256, bn = (swz % (N_DIM/256))*256;

  // per-lane ds_read bases; element (row,k) at byte row*128 + ((k/8)^(row&7))*16 + (k%8)*2
  const int l15 = lane & 15, l4 = lane >> 4, l7 = lane & 7;
  const int s0 = ((l4)     ^ l7) * 16;      // kk=0 slot byte
  const int s1 = ((4 + l4) ^ l7) * 16;      // kk=1 slot byte
  const char* pA0 = ldsb + (wr + l15)*128 + s0;
  const char* pA1 = ldsb + (wr + l15)*128 + s1;
  const char* pB0 = ldsb + 32768 + (wc + l15)*128 + s0;
  const char* pB1 = ldsb + 32768 + (wc + l15)*128 + s1;

  // staging: thread covers 16B; row=tid>>3, slot=tid&7, pre-swizzled global k-slot
  const int gks = (tid & 7) ^ ((tid >> 3) & 7);
  const size_t gArow = (size_t)(bm + (tid>>3))*K_DIM + gks*8;
  const size_t gBrow = (size_t)(bn + (tid>>3))*K_DIM + gks*8;

  f32x4 acc[4][8];
  #pragma unroll
  for (int i=0;i<4;i++)
    #pragma unroll
    for (int j=0;j<8;j++) acc[i][j] = (f32x4){0.f,0.f,0.f,0.f};

  // stage half h (0/1) of A or B for K-tile tt
#define STAGE_A(h, tt) do{ \
    const ushort* g = gA + gArow + (size_t)(h)*128*K_DIM + (tt)*BK; \
    char* d = ldsb + ((tt)&1)*BUF + (h)*16384 + tid*16; \
    GLOAD(g, d); GLOAD(g + (size_t)64*K_DIM, d + 8192); \
  }while(0)
#define STAGE_B(h, tt) do{ \
    const ushort* g = gB + gBrow + (size_t)(h)*128*K_DIM + (tt)*BK; \
    char* d = ldsb + ((tt)&1)*BUF + 32768 + (h)*16384 + tid*16; \
    GLOAD(g, d); GLOAD(g + (size_t)64*K_DIM, d + 8192); \
  }while(0)

#define RD_A(dst, QA, bo) { _Pragma("unroll") \
    for (int fr=0; fr<4; ++fr){ \
      dst[fr][0] = *(const bf16x8*)(pA0 + (bo) + (QA)*16384 + fr*2048); \
      dst[fr][1] = *(const bf16x8*)(pA1 + (bo) + (QA)*16384 + fr*2048); } }
#define RD_B(QB, bo) { _Pragma("unroll") \
    for (int fc=0; fc<2; ++fc){ \
      b[fc][0] = *(const bf16x8*)(pB0 + (bo) + (QB)*16384 + fc*2048); \
      b[fc][1] = *(const bf16x8*)(pB1 + (bo) + (QB)*16384 + fc*2048); } }
#define MFMA_Q(qi, asrc) { \
    __builtin_amdgcn_s_setprio(1); \
    _Pragma("unroll") \
    for (int fr=0; fr<4; ++fr) \
      _Pragma("unroll") \
      for (int fc=0; fc<2; ++fc){ \
        acc[qi][fr*2+fc] = __builtin_amdgcn_mfma_f32_16x16x32_bf16(asrc[fr][0], b[fc][0], acc[qi][fr*2+fc], 0,0,0); \
        acc[qi][fr*2+fc] = __builtin_amdgcn_mfma_f32_16x16x32_bf16(asrc[fr][1], b[fc][1], acc[qi][fr*2+fc], 0,0,0); } \
    __builtin_amdgcn_s_setprio(0); }
#define BAR() asm volatile("" ::: "memory"); __builtin_amdgcn_s_barrier(); asm volatile("" ::: "memory")
#define VM(n) asm volatile("s_waitcnt vmcnt(" #n ")" ::: "memory")

  bf16x8 a0[4][2], a1[4][2], b[2][2];

  // prologue: stage all 4 halves of tile 0; force Ah0,Bh0
  STAGE_A(0,0); STAGE_B(0,0); STAGE_A(1,0); STAGE_B(1,0);
  VM(4); BAR();

  // vmcnt bookkeeping (per-wave FIFO, 2 loads per STAGE):
  //  P0 entry outstanding: [A1(t),B1(t)]. +A0' -> 6; VM(4) forces A1(t) (read in P1).
  //  P1: +B0' -> 6; VM(4) forces B1(t) (read in P2).
  //  P2: +A1' -> 6; VM(6) no-op (P3 reads nothing).
  //  P3: +B1' -> 8; VM(4) forces A0'(t+1) AND B0'(t+1) (read in P0 of t+1).
  for (int t = 0; t < NKT-1; ++t) {
    const int bo = (t&1)*BUF;
    // P0: quad (0,0) — read Ah0-frags + Bh0-frags; stage Ah0(t+1)
    RD_A(a0, 0, bo); RD_B(0, bo);
    STAGE_A(0, t+1);
    VM(4); BAR();
    MFMA_Q(0, a0); BAR();
    // P1: quad (1,0) — read Ah1-frags (B reused); stage Bh0(t+1)
    RD_A(a1, 1, bo);
    STAGE_B(0, t+1);
    VM(4); BAR();
    MFMA_Q(2, a1); BAR();
    // P2: quad (1,1) — read Bh1-frags (A1 reused); stage Ah1(t+1)
    RD_B(1, bo);
    STAGE_A(1, t+1);
    VM(6); BAR();
    MFMA_Q(3, a1); BAR();
    // P3: quad (0,1) — a0 persisted, b reused; stage Bh1(t+1)
    STAGE_B(1, t+1);
    VM(4); BAR();
    MFMA_Q(1, a0); BAR();
  }
  { // peeled last tile: no staging; drain progressively
    const int bo = ((NKT-1)&1)*BUF;
    RD_A(a0, 0, bo); RD_B(0, bo);
    VM(2); BAR();
    MFMA_Q(0, a0); BAR();
    RD_A(a1, 1, bo);
    VM(0); BAR();
    MFMA_Q(2, a1); BAR();
    RD_B(1, bo);
    BAR();
    MFMA_Q(3, a1); BAR();
    MFMA_Q(1, a0); BAR();
  }

  // ---- epilogue: acc -> LDS (bf16, bias+sigmoid) -> coalesced stores ----
  const int region = bn >> 10;
  ushort* dst = region==0 ? xbuf : (region==1 ? zbuf : hbuf);
  ushort* lds16 = (ushort*)ldsb;
  float bv[2][2];
  #pragma unroll
  for (int qb=0; qb<2; ++qb)
    #pragma unroll
    for (int fc=0; fc<2; ++fc)
      bv[qb][fc] = bias[bn + qb*128 + wc + fc*16 + l15];

  #pragma unroll
  for (int qa=0; qa<2; ++qa)
    #pragma unroll
    for (int qb=0; qb<2; ++qb){
      const int qi = qa*2+qb;
      #pragma unroll
      for (int fr=0; fr<4; ++fr)
        #pragma unroll
        for (int fc=0; fc<2; ++fc)
          #pragma unroll
          for (int r=0; r<4; ++r){
            int row = qa*128 + wr + fr*16 + l4*4 + r;
            int col = qb*128 + wc + fc*16 + l15;
            float v = acc[qi][fr*2+fc][r] + bv[qb][fc];
            if (region) v = 1.f/(1.f + __expf(-v));
            lds16[row*256 + col] = f2bf(v);
          }
    }
  __syncthreads();
  const int cb = bn & (D_DIM-1);
  #pragma unroll
  for (int i=0;i<16;i++){
    int off = i*8192 + tid*16;                 // byte in 256x256 bf16 tile
    int row = off >> 9;
    int cols = (off & 511) >> 1;
    *(uint4*)(dst + (size_t)(bm+row)*D_DIM + cb + cols) = *(const uint4*)(ldsb + off);
  }
#undef STAGE_A
#undef STAGE_B
#undef RD_A
#undef RD_B
#undef MFMA_Q
#undef BAR
#undef VM
}

// Pass 1: per (segment, 8-channel group) compose affine coefficients
__global__ __launch_bounds__(256) void scan_pass1(
    const ushort* __restrict__ z, const ushort* __restrict__ x,
    float* __restrict__ Aout, float* __restrict__ Bout)
{
  int t = blockIdx.x*256 + threadIdx.x;   // 0..131071
  int cg = t & (CG-1), g = t >> 11;       // CG = 2048 = 2^11
  int c0 = cg*8;
  size_t base = (size_t)g*SEGLEN*NCH + c0;
  float A[8], Bc[8];
  #pragma unroll
  for (int j=0;j<8;j++){ A[j]=1.f; Bc[j]=0.f; }
  #pragma unroll 4
  for (int i=0;i<SEGLEN;i++){
    uint4 zv = *(const uint4*)(z + base + (size_t)i*NCH);
    uint4 xv = *(const uint4*)(x + base + (size_t)i*NCH);
    const ushort* zp = (const ushort*)&zv;
    const ushort* xp = (const ushort*)&xv;
    #pragma unroll
    for (int j=0;j<8;j++){
      float zf = bf2f(zp[j]);
      float a  = 1.f - zf;
      float bb = zf * bf2f(xp[j]);
      Bc[j] = a*Bc[j] + bb;
      A[j]  = a*A[j];
    }
  }
  float* Ao = Aout + (size_t)g*NCH + c0;
  float* Bo = Bout + (size_t)g*NCH + c0;
  *(float4*)Ao     = make_float4(A[0],A[1],A[2],A[3]);
  *(float4*)(Ao+4) = make_float4(A[4],A[5],A[6],A[7]);
  *(float4*)Bo     = make_float4(Bc[0],Bc[1],Bc[2],Bc[3]);
  *(float4*)(Bo+4) = make_float4(Bc[4],Bc[5],Bc[6],Bc[7]);
}

// Pass 2: sequential scan over the 64 segment summaries per channel
__global__ __launch_bounds__(256) void scan_pass2(
    const float* __restrict__ A, const float* __restrict__ B,
    const float* __restrict__ h0, float* __restrict__ seg, float* __restrict__ hfin)
{
  int c = blockIdx.x*256 + threadIdx.x;   // 0..16383
  float s = h0[c];
  #pragma unroll 8
  for (int g=0; g<SEG; g++){
    seg[(size_t)g*NCH + c] = s;
    s = A[(size_t)g*NCH + c]*s + B[(size_t)g*NCH + c];
  }
  hfin[c] = s;
}

// Pass 3: replay each segment from its start state, fused output blend
__global__ __launch_bounds__(256) void scan_pass3(
    const ushort* __restrict__ z, const ushort* __restrict__ x, const ushort* __restrict__ hg,
    const float* __restrict__ prev, const float* __restrict__ seg,
    float* __restrict__ out)
{
  int t = blockIdx.x*256 + threadIdx.x;   // 0..131071
  int cg = t & (CG-1), g = t >> 11;
  int c0 = cg*8;
  float s[8];
  *(float4*)s     = *(const float4*)(seg + (size_t)g*NCH + c0);
  *(float4*)(s+4) = *(const float4*)(seg + (size_t)g*NCH + c0 + 4);
  size_t base = (size_t)g*SEGLEN*NCH + c0;
  #pragma unroll 2
  for (int i=0;i<SEGLEN;i++){
    size_t idx = base + (size_t)i*NCH;
    uint4 zv = *(const uint4*)(z+idx);
    uint4 xv = *(const uint4*)(x+idx);
    uint4 hv = *(const uint4*)(hg+idx);
    float4 p0 = *(const float4*)(prev+idx);
    float4 p1 = *(const float4*)(prev+idx+4);
    const ushort* zp=(const ushort*)&zv;
    const ushort* xp=(const ushort*)&xv;
    const ushort* hp=(const ushort*)&hv;
    float pv[8] = {p0.x,p0.y,p0.z,p0.w,p1.x,p1.y,p1.z,p1.w};
    float o[8];
    #pragma unroll
    for (int j=0;j<8;j++){
      float zf = bf2f(zp[j]);
      s[j] += zf*(bf2f(xp[j]) - s[j]);
      float hf = bf2f(hp[j]);
      o[j] = s[j] + hf*(pv[j] - s[j]);
    }
    *(float4*)(out+idx)   = make_float4(o[0],o[1],o[2],o[3]);
    *(float4*)(out+idx+4) = make_float4(o[4],o[5],o[6],o[7]);
  }
}

extern "C" void kernel_launch(void* const* d_in, const int* in_sizes, int n_in,
                              void* d_out, int out_size, void* d_ws, size_t ws_size,
                              hipStream_t stream) {
  const float* prev = (const float*)d_in[0];   // (L,B,D)
  const float* h0   = (const float*)d_in[1];   // (B,D)
  const float* W    = (const float*)d_in[2];   // (3D,D)
  const float* bias = (const float*)d_in[3];   // (3D,)
  float* out  = (float*)d_out;
  float* hfin = out + (size_t)M_DIM*D_DIM;

  char* ws = (char*)d_ws;
  ushort* Ab = (ushort*)ws;                                        // 64 MiB (dead after gemm)
  ushort* Wb = (ushort*)(ws + (size_t)M_DIM*K_DIM*2);              // 6 MiB
  ushort* xb = (ushort*)(ws + (size_t)M_DIM*K_DIM*2 + (size_t)N_DIM*K_DIM*2);
  ushort* zb = xb + (size_t)M_DIM*D_DIM;
  ushort* hb = zb + (size_t)M_DIM*D_DIM;
  // overlay scan scratch on Ab's region (only live after gemm completes)
  float* Abuf = (float*)ws;                     // SEG*NCH floats = 4 MiB
  float* Bbuf = Abuf + (size_t)SEG*NCH;         // 4 MiB
  float* segb = Bbuf + (size_t)SEG*NCH;         // 4 MiB

  cvt8<<<(M_DIM*K_DIM/8 + 255)/256, 256, 0, stream>>>(prev, Ab, M_DIM*K_DIM/8);
  cvt8<<<(N_DIM*K_DIM/8 + 255)/256, 256, 0, stream>>>(W,    Wb, N_DIM*K_DIM/8);
  gemm_sru<<<(M_DIM/256)*(N_DIM/256), 512, 0, stream>>>(Ab, Wb, bias, xb, zb, hb);
  scan_pass1<<<(CG*SEG)/256, 256, 0, stream>>>(zb, xb, Abuf, Bbuf);
  scan_pass2<<<NCH/256, 256, 0, stream>>>(Abuf, Bbuf, h0, segb, hfin);
  scan_pass3<<<(CG*SEG)/256, 256, 0, stream>>>(zb, xb, hb, prev, segb, out);
}